// Round 1
// baseline (255.856 us; speedup 1.0000x reference)
//
#include <hip/hip_runtime.h>

// Problem constants (B=16, T=2048, D=512, A=128)
#define NB 16
#define NT 2048
#define ND 512
#define NA 128
#define EPSV 1e-6f
#define SCALE 0.08838834764831845f  // 128^-0.5

typedef __bf16 bf16;
typedef __bf16 bf16x4 __attribute__((ext_vector_type(4)));
typedef __bf16 bf16x8 __attribute__((ext_vector_type(8)));
typedef float f32x4 __attribute__((ext_vector_type(4)));

// ---------------------------------------------------------------------------
// Kernel 0: build W^T bf16 [256][512]  (rows 0..127 = Wq cols, 128..255 = Wk)
// ---------------------------------------------------------------------------
__global__ void prep_wt(const float* __restrict__ Wq, const float* __restrict__ Wk,
                        bf16* __restrict__ WT) {
    int n = blockIdx.x;                    // output row = projection column, 0..255
    const float* W = (n < NA) ? Wq : Wk;
    int col = n & (NA - 1);
    for (int k = threadIdx.x; k < ND; k += blockDim.x)
        WT[(size_t)n * ND + k] = (bf16)W[(size_t)k * NA + col];
}

// ---------------------------------------------------------------------------
// Kernel 1: fused norm + V + QK projection GEMM (M=32768, N=256, K=512)
// Block: 256 threads (4 waves), 64 rows. xn staged bf16 in swizzled LDS.
// ---------------------------------------------------------------------------
__launch_bounds__(256)
__global__ void norm_proj(const float* __restrict__ x, const float* __restrict__ Wv,
                          const float* __restrict__ bvp, const bf16* __restrict__ WT,
                          const float* __restrict__ bq, const float* __restrict__ bk,
                          bf16* __restrict__ QK, float* __restrict__ Vout) {
    __shared__ bf16 xn[64 * ND];  // 64 KB, XOR-swizzled rows
    const int tid = threadIdx.x;
    const int lane = tid & 63, wv = tid >> 6;
    const int row0 = blockIdx.x * 64;

    // per-lane Wv slice (reused across 16 rows): elems 4l..4l+3 and 256+4l..+3
    float wvv[8];
    float sumw = 0.f;
#pragma unroll
    for (int i = 0; i < 4; ++i) { wvv[i]     = Wv[lane * 4 + i];       sumw += wvv[i]; }
#pragma unroll
    for (int i = 0; i < 4; ++i) { wvv[4 + i] = Wv[256 + lane * 4 + i]; sumw += wvv[4 + i]; }
#pragma unroll
    for (int m = 1; m < 64; m <<= 1) sumw += __shfl_xor(sumw, m);
    const float bvs = bvp[0];

    // Phase A: norm 16 rows per wave, write xn bf16 to swizzled LDS
    for (int r = 0; r < 16; ++r) {
        const int lrow = wv * 16 + r;
        const int grow = row0 + lrow;
        const float* xr = x + (size_t)grow * ND;
        f32x4 a = *(const f32x4*)(xr + lane * 4);        // elems 4l..4l+3
        f32x4 b = *(const f32x4*)(xr + 256 + lane * 4);  // elems 256+4l..
        float s = 0.f, sq = 0.f, dw = 0.f;
#pragma unroll
        for (int i = 0; i < 4; ++i) { s += a[i]; sq += a[i] * a[i]; dw += a[i] * wvv[i]; }
#pragma unroll
        for (int i = 0; i < 4; ++i) { s += b[i]; sq += b[i] * b[i]; dw += b[i] * wvv[4 + i]; }
#pragma unroll
        for (int m = 1; m < 64; m <<= 1) {
            s  += __shfl_xor(s, m);
            sq += __shfl_xor(sq, m);
            dw += __shfl_xor(dw, m);
        }
        const float mu  = s * (1.f / 512.f);
        float var = (sq - 512.f * mu * mu) * (1.f / 511.f);
        var = fmaxf(var, 0.f);
        const float inv = 1.f / (sqrtf(var) + EPSV);
        if (lane == 0) Vout[grow] = (dw - mu * sumw) * inv + bvs;

        const int sw = (lrow & 7) << 4;
        bf16x4 v0, v1;
#pragma unroll
        for (int i = 0; i < 4; ++i) v0[i] = (bf16)((a[i] - mu) * inv);
#pragma unroll
        for (int i = 0; i < 4; ++i) v1[i] = (bf16)((b[i] - mu) * inv);
        *(bf16x4*)((char*)xn + lrow * 1024 + ((lane * 8) ^ sw))       = v0;
        *(bf16x4*)((char*)xn + lrow * 1024 + ((512 + lane * 8) ^ sw)) = v1;
    }
    __syncthreads();

    // Phase B: MFMA GEMM. Each wave: 16 rows x 256 cols.
    const int c = lane & 15, g = lane >> 4;
    const int arow = wv * 16 + c;
    const int asw = (arow & 7) << 4;
    f32x4 acc[16];
#pragma unroll
    for (int ns = 0; ns < 16; ++ns) acc[ns] = f32x4{0.f, 0.f, 0.f, 0.f};

    for (int ks = 0; ks < 16; ++ks) {
        const bf16x8 af = *(const bf16x8*)((const char*)xn + arow * 1024 +
                                           ((ks * 64 + g * 16) ^ asw));
#pragma unroll
        for (int h = 0; h < 2; ++h) {
            bf16x8 bfr[8];
#pragma unroll
            for (int i = 0; i < 8; ++i) {
                const int n = (h * 8 + i) * 16 + c;
                bfr[i] = *(const bf16x8*)(WT + (size_t)n * ND + ks * 32 + g * 8);
            }
#pragma unroll
            for (int i = 0; i < 8; ++i)
                acc[h * 8 + i] = __builtin_amdgcn_mfma_f32_16x16x32_bf16(
                    af, bfr[i], acc[h * 8 + i], 0, 0, 0);
        }
    }
    // Epilogue: bias + bf16 store.  D layout: row=g*4+j, col=c (verified m89)
#pragma unroll
    for (int ns = 0; ns < 16; ++ns) {
        const int n = ns * 16 + c;
        const float bias = (n < NA) ? bq[n] : bk[n - NA];
#pragma unroll
        for (int j = 0; j < 4; ++j) {
            const int lrow = wv * 16 + g * 4 + j;
            QK[(size_t)(row0 + lrow) * 256 + n] = (bf16)(acc[ns][j] + bias);
        }
    }
}

// ---------------------------------------------------------------------------
// Kernel 2: attention. Block = 256 thr (4 waves), 64 t-rows per block,
// wave owns 16 rows. Two passes over K-tiles (SN=64) staged in swizzled LDS.
// ---------------------------------------------------------------------------
__launch_bounds__(256)
__global__ void attn(const bf16* __restrict__ QK, const float* __restrict__ Vg,
                     float* __restrict__ out_w, float* __restrict__ out_att) {
    __shared__ bf16 Kt[64 * NA];  // 16 KB, XOR-swizzled
    __shared__ float Vt[64];
    const int tid = threadIdx.x;
    const int lane = tid & 63, wv = tid >> 6;
    const int b = blockIdx.y, t0 = blockIdx.x * 64;
    const int trow_base = t0 + wv * 16;
    const int c = lane & 15, g = lane >> 4;

    // Q fragments in registers for both passes: A-op row = c, k = ks*32 + g*8
    bf16x8 qf[4];
    const bf16* qrow = QK + (size_t)(b * NT + trow_base + c) * 256;
#pragma unroll
    for (int ks = 0; ks < 4; ++ks) qf[ks] = *(const bf16x8*)(qrow + ks * 32 + g * 8);

    float m[4], l[4], wacc[4];
#pragma unroll
    for (int j = 0; j < 4; ++j) { m[j] = -3.0e38f; l[j] = 0.f; wacc[j] = 0.f; }

    // ---- Pass 1: online row max / sum / w accumulation ----
    for (int s0 = 0; s0 < NT; s0 += 64) {
        __syncthreads();
        for (int cch = tid; cch < 1024; cch += 256) {
            const int row = cch >> 4, cc = cch & 15;
            *(bf16x8*)((char*)Kt + row * 256 + ((cc * 16) ^ ((row & 7) << 4))) =
                *(const bf16x8*)(QK + (size_t)(b * NT + s0 + row) * 256 + NA + cc * 8);
        }
        if (tid < 64) Vt[tid] = Vg[b * NT + s0 + tid];
        __syncthreads();

        float sv[4][4];
#pragma unroll
        for (int ns = 0; ns < 4; ++ns) {
            f32x4 acc = f32x4{0.f, 0.f, 0.f, 0.f};
            const int rr = ns * 16 + c;
            const int rsw = (rr & 7) << 4;
#pragma unroll
            for (int ks = 0; ks < 4; ++ks) {
                const bf16x8 bfr = *(const bf16x8*)((const char*)Kt + rr * 256 +
                                                    ((ks * 64 + g * 16) ^ rsw));
                acc = __builtin_amdgcn_mfma_f32_16x16x32_bf16(qf[ks], bfr, acc, 0, 0, 0);
            }
#pragma unroll
            for (int j = 0; j < 4; ++j) sv[ns][j] = acc[j] * SCALE;
        }
#pragma unroll
        for (int j = 0; j < 4; ++j) {
            float cm = fmaxf(fmaxf(sv[0][j], sv[1][j]), fmaxf(sv[2][j], sv[3][j]));
#pragma unroll
            for (int mm = 1; mm < 16; mm <<= 1) cm = fmaxf(cm, __shfl_xor(cm, mm));
            const float nm = fmaxf(m[j], cm);
            const float alpha = __expf(m[j] - nm);
            float ps = 0.f, pv = 0.f;
#pragma unroll
            for (int ns = 0; ns < 4; ++ns) {
                const float p = __expf(sv[ns][j] - nm);
                ps += p;
                pv += p * Vt[ns * 16 + c];
            }
#pragma unroll
            for (int mm = 1; mm < 16; mm <<= 1) {
                ps += __shfl_xor(ps, mm);
                pv += __shfl_xor(pv, mm);
            }
            l[j] = l[j] * alpha + ps;
            wacc[j] = wacc[j] * alpha + pv;
            m[j] = nm;
        }
    }
    float invl[4];
#pragma unroll
    for (int j = 0; j < 4; ++j) invl[j] = 1.f / l[j];
    if (c == 0) {
#pragma unroll
        for (int j = 0; j < 4; ++j)
            out_w[b * NT + trow_base + g * 4 + j] = wacc[j] * invl[j];
    }

    // ---- Pass 2: recompute scores, write normalized w_att ----
    for (int s0 = 0; s0 < NT; s0 += 64) {
        __syncthreads();
        for (int cch = tid; cch < 1024; cch += 256) {
            const int row = cch >> 4, cc = cch & 15;
            *(bf16x8*)((char*)Kt + row * 256 + ((cc * 16) ^ ((row & 7) << 4))) =
                *(const bf16x8*)(QK + (size_t)(b * NT + s0 + row) * 256 + NA + cc * 8);
        }
        __syncthreads();
#pragma unroll
        for (int ns = 0; ns < 4; ++ns) {
            f32x4 acc = f32x4{0.f, 0.f, 0.f, 0.f};
            const int rr = ns * 16 + c;
            const int rsw = (rr & 7) << 4;
#pragma unroll
            for (int ks = 0; ks < 4; ++ks) {
                const bf16x8 bfr = *(const bf16x8*)((const char*)Kt + rr * 256 +
                                                    ((ks * 64 + g * 16) ^ rsw));
                acc = __builtin_amdgcn_mfma_f32_16x16x32_bf16(qf[ks], bfr, acc, 0, 0, 0);
            }
#pragma unroll
            for (int j = 0; j < 4; ++j) {
                const float w = __expf(acc[j] * SCALE - m[j]) * invl[j];
                out_att[(size_t)(b * NT + trow_base + g * 4 + j) * NT + s0 + ns * 16 + c] = w;
            }
        }
    }
}

// ---------------------------------------------------------------------------
extern "C" void kernel_launch(void* const* d_in, const int* in_sizes, int n_in,
                              void* d_out, int out_size, void* d_ws, size_t ws_size,
                              hipStream_t stream) {
    const float* x  = (const float*)d_in[0];
    const float* Wq = (const float*)d_in[1];
    const float* bq = (const float*)d_in[2];
    const float* Wk = (const float*)d_in[3];
    const float* bk = (const float*)d_in[4];
    const float* Wv = (const float*)d_in[5];
    const float* bv = (const float*)d_in[6];

    float* out_w   = (float*)d_out;            // [B,T,1] = 32768
    float* out_att = (float*)d_out + NB * NT;  // [B,T,T]

    char* ws = (char*)d_ws;
    bf16*  WT  = (bf16*)ws;                          // 256*512*2   = 262144 B
    float* V   = (float*)(ws + 262144);              // 32768*4     = 131072 B
    bf16*  QK  = (bf16*)(ws + 262144 + 131072);      // 32768*256*2 = 16 MB

    prep_wt<<<dim3(256), dim3(256), 0, stream>>>(Wq, Wk, WT);
    norm_proj<<<dim3((NB * NT) / 64), dim3(256), 0, stream>>>(x, Wv, bv, WT, bq, bk, QK, V);
    attn<<<dim3(NT / 64, NB), dim3(256), 0, stream>>>(QK, V, out_w, out_att);
}

// Round 2
// 197.915 us; speedup vs baseline: 1.2928x; 1.2928x over previous
//
#include <hip/hip_runtime.h>

// Problem constants (B=16, T=2048, D=512, A=128)
#define NB 16
#define NT 2048
#define ND 512
#define NA 128
#define EPSV 1e-6f
#define SCALE 0.08838834764831845f  // 128^-0.5
#define NCH 4        // s-chunks in attention
#define SCH 512      // s-chunk length

typedef __bf16 bf16;
typedef __bf16 bf16x4 __attribute__((ext_vector_type(4)));
typedef __bf16 bf16x8 __attribute__((ext_vector_type(8)));
typedef float f32x4 __attribute__((ext_vector_type(4)));

// ---------------------------------------------------------------------------
// Kernel 0: build W^T bf16 [256][512]  (rows 0..127 = Wq cols, 128..255 = Wk)
// ---------------------------------------------------------------------------
__global__ void prep_wt(const float* __restrict__ Wq, const float* __restrict__ Wk,
                        bf16* __restrict__ WT) {
    int n = blockIdx.x;
    const float* W = (n < NA) ? Wq : Wk;
    int col = n & (NA - 1);
    for (int k = threadIdx.x; k < ND; k += blockDim.x)
        WT[(size_t)n * ND + k] = (bf16)W[(size_t)k * NA + col];
}

// ---------------------------------------------------------------------------
// Kernel 1: fused norm + V + QK projection GEMM. 16 rows/block, grid 2048.
// ---------------------------------------------------------------------------
__launch_bounds__(256)
__global__ void norm_proj(const float* __restrict__ x, const float* __restrict__ Wv,
                          const float* __restrict__ bvp, const bf16* __restrict__ WT,
                          const float* __restrict__ bq, const float* __restrict__ bk,
                          bf16* __restrict__ QK, float* __restrict__ Vout) {
    __shared__ bf16 xn[16 * ND];  // 16 KB, XOR-swizzled rows
    const int tid = threadIdx.x;
    const int lane = tid & 63, wv = tid >> 6;
    const int row0 = blockIdx.x * 16;

    float wvv[8];
    float sumw = 0.f;
#pragma unroll
    for (int i = 0; i < 4; ++i) { wvv[i]     = Wv[lane * 4 + i];       sumw += wvv[i]; }
#pragma unroll
    for (int i = 0; i < 4; ++i) { wvv[4 + i] = Wv[256 + lane * 4 + i]; sumw += wvv[4 + i]; }
#pragma unroll
    for (int m = 1; m < 64; m <<= 1) sumw += __shfl_xor(sumw, m);
    const float bvs = bvp[0];

    // Phase A: wave wv norms rows wv*4 .. wv*4+3
#pragma unroll
    for (int r = 0; r < 4; ++r) {
        const int lrow = wv * 4 + r;
        const int grow = row0 + lrow;
        const float* xr = x + (size_t)grow * ND;
        f32x4 a = *(const f32x4*)(xr + lane * 4);
        f32x4 b = *(const f32x4*)(xr + 256 + lane * 4);
        float s = 0.f, sq = 0.f, dw = 0.f;
#pragma unroll
        for (int i = 0; i < 4; ++i) { s += a[i]; sq += a[i] * a[i]; dw += a[i] * wvv[i]; }
#pragma unroll
        for (int i = 0; i < 4; ++i) { s += b[i]; sq += b[i] * b[i]; dw += b[i] * wvv[4 + i]; }
#pragma unroll
        for (int m = 1; m < 64; m <<= 1) {
            s  += __shfl_xor(s, m);
            sq += __shfl_xor(sq, m);
            dw += __shfl_xor(dw, m);
        }
        const float mu  = s * (1.f / 512.f);
        float var = (sq - 512.f * mu * mu) * (1.f / 511.f);
        var = fmaxf(var, 0.f);
        const float inv = 1.f / (sqrtf(var) + EPSV);
        if (lane == 0) Vout[grow] = (dw - mu * sumw) * inv + bvs;

        const int sw = (lrow & 7) << 4;
        bf16x4 v0, v1;
#pragma unroll
        for (int i = 0; i < 4; ++i) v0[i] = (bf16)((a[i] - mu) * inv);
#pragma unroll
        for (int i = 0; i < 4; ++i) v1[i] = (bf16)((b[i] - mu) * inv);
        *(bf16x4*)((char*)xn + lrow * 1024 + ((lane * 8) ^ sw))       = v0;
        *(bf16x4*)((char*)xn + lrow * 1024 + ((512 + lane * 8) ^ sw)) = v1;
    }
    __syncthreads();

    // Phase B: wave wv computes cols wv*64 .. +63 for all 16 rows
    const int c = lane & 15, g = lane >> 4;
    const int asw = (c & 7) << 4;
    f32x4 acc[4];
#pragma unroll
    for (int i = 0; i < 4; ++i) acc[i] = f32x4{0.f, 0.f, 0.f, 0.f};

    for (int ks = 0; ks < 16; ++ks) {
        const bf16x8 af = *(const bf16x8*)((const char*)xn + c * 1024 +
                                           ((ks * 64 + g * 16) ^ asw));
#pragma unroll
        for (int i = 0; i < 4; ++i) {
            const int n = wv * 64 + i * 16 + c;
            const bf16x8 bfr = *(const bf16x8*)(WT + (size_t)n * ND + ks * 32 + g * 8);
            acc[i] = __builtin_amdgcn_mfma_f32_16x16x32_bf16(af, bfr, acc[i], 0, 0, 0);
        }
    }
#pragma unroll
    for (int i = 0; i < 4; ++i) {
        const int n = wv * 64 + i * 16 + c;
        const float bias = (n < NA) ? bq[n] : bk[n - NA];
#pragma unroll
        for (int j = 0; j < 4; ++j)
            QK[(size_t)(row0 + g * 4 + j) * 256 + n] = (bf16)(acc[i][j] + bias);
    }
}

// ---------------------------------------------------------------------------
// Kernel 2: pass1 — per-chunk online softmax stats (m, l, w-partial).
// Grid (32 t-blocks, 4 s-chunks, 16 b). Swapped MFMA: lane-local s-subsets.
// ---------------------------------------------------------------------------
__launch_bounds__(256)
__global__ void attn_pass1(const bf16* __restrict__ QK, const float* __restrict__ Vg,
                           float* __restrict__ pm, float* __restrict__ pl,
                           float* __restrict__ pw) {
    __shared__ bf16 Kt[64 * NA];  // 16 KB, XOR-swizzled
    const int tid = threadIdx.x;
    const int lane = tid & 63, wv = tid >> 6;
    const int b = blockIdx.z, t0 = blockIdx.x * 64, sc = blockIdx.y;
    const int c = lane & 15, g = lane >> 4;
    const int trow = t0 + wv * 16 + c;

    bf16x8 qf[4];
    const bf16* qrow = QK + (size_t)(b * NT + trow) * 256;
#pragma unroll
    for (int ks = 0; ks < 4; ++ks) qf[ks] = *(const bf16x8*)(qrow + ks * 32 + g * 8);

    const float* vbase = Vg + b * NT + sc * SCH;

    float m_loc = -3.0e38f, l_loc = 0.f, w_loc = 0.f;

    for (int tt = 0; tt < SCH / 64; ++tt) {
        const int s0 = sc * SCH + tt * 64;
        __syncthreads();
        for (int cch = tid; cch < 1024; cch += 256) {
            const int row = cch >> 4, cc = cch & 15;
            *(bf16x8*)((char*)Kt + row * 256 + ((cc * 16) ^ ((row & 7) << 4))) =
                *(const bf16x8*)(QK + (size_t)(b * NT + s0 + row) * 256 + NA + cc * 8);
        }
        __syncthreads();

        float sv[16];
        f32x4 vv[4];
#pragma unroll
        for (int ns = 0; ns < 4; ++ns) {
            f32x4 acc = f32x4{0.f, 0.f, 0.f, 0.f};
            const int rr = ns * 16 + c;
            const int rsw = (rr & 7) << 4;
#pragma unroll
            for (int ks = 0; ks < 4; ++ks) {
                const bf16x8 afr = *(const bf16x8*)((const char*)Kt + rr * 256 +
                                                    ((ks * 64 + g * 16) ^ rsw));
                acc = __builtin_amdgcn_mfma_f32_16x16x32_bf16(afr, qf[ks], acc, 0, 0, 0);
            }
#pragma unroll
            for (int jj = 0; jj < 4; ++jj) sv[ns * 4 + jj] = acc[jj] * SCALE;
            vv[ns] = *(const f32x4*)(vbase + tt * 64 + ns * 16 + g * 4);
        }
        // lane-local online update over 16 s-values (s = s0 + ns*16 + g*4 + jj)
        float cm = sv[0];
#pragma unroll
        for (int i = 1; i < 16; ++i) cm = fmaxf(cm, sv[i]);
        const float nm = fmaxf(m_loc, cm);
        const float alpha = __expf(m_loc - nm);
        float ps = 0.f, pv = 0.f;
#pragma unroll
        for (int ns = 0; ns < 4; ++ns)
#pragma unroll
            for (int jj = 0; jj < 4; ++jj) {
                const float p = __expf(sv[ns * 4 + jj] - nm);
                ps += p;
                pv += p * vv[ns][jj];
            }
        l_loc = l_loc * alpha + ps;
        w_loc = w_loc * alpha + pv;
        m_loc = nm;
    }

    // merge partials across the 4 g-lanes sharing trow
#pragma unroll
    for (int mask = 16; mask <= 32; mask <<= 1) {
        const float mo = __shfl_xor(m_loc, mask);
        const float lo = __shfl_xor(l_loc, mask);
        const float wo = __shfl_xor(w_loc, mask);
        const float nm = fmaxf(m_loc, mo);
        const float a1 = __expf(m_loc - nm), a2 = __expf(mo - nm);
        l_loc = l_loc * a1 + lo * a2;
        w_loc = w_loc * a1 + wo * a2;
        m_loc = nm;
    }
    if (g == 0) {
        const int idx = sc * (NB * NT) + b * NT + trow;
        pm[idx] = m_loc;
        pl[idx] = l_loc;
        pw[idx] = w_loc;
    }
}

// ---------------------------------------------------------------------------
// Kernel 3: merge the 4 chunk-partials -> m_final, 1/l, out_w
// ---------------------------------------------------------------------------
__global__ void attn_reduce(const float* __restrict__ pm, const float* __restrict__ pl,
                            const float* __restrict__ pw, float* __restrict__ mfin,
                            float* __restrict__ linv, float* __restrict__ out_w) {
    const int r = blockIdx.x * 256 + threadIdx.x;  // 0 .. NB*NT-1
    float mv[NCH], lv[NCH], wvp[NCH];
#pragma unroll
    for (int ch = 0; ch < NCH; ++ch) {
        mv[ch] = pm[ch * (NB * NT) + r];
        lv[ch] = pl[ch * (NB * NT) + r];
        wvp[ch] = pw[ch * (NB * NT) + r];
    }
    float M = mv[0];
#pragma unroll
    for (int ch = 1; ch < NCH; ++ch) M = fmaxf(M, mv[ch]);
    float L = 0.f, W = 0.f;
#pragma unroll
    for (int ch = 0; ch < NCH; ++ch) {
        const float a = __expf(mv[ch] - M);
        L += lv[ch] * a;
        W += wvp[ch] * a;
    }
    mfin[r] = M;
    linv[r] = 1.f / L;
    out_w[r] = W / L;
}

// ---------------------------------------------------------------------------
// Kernel 4: pass2 — recompute scores, write normalized w_att.
// Grid (32 t-blocks, 4 s-chunks, 16 b). f32x4 coalesced stores.
// ---------------------------------------------------------------------------
__launch_bounds__(256)
__global__ void attn_pass2(const bf16* __restrict__ QK, const float* __restrict__ mfin,
                           const float* __restrict__ linv, float* __restrict__ out_att) {
    __shared__ bf16 Kt[64 * NA];
    const int tid = threadIdx.x;
    const int lane = tid & 63, wv = tid >> 6;
    const int b = blockIdx.z, t0 = blockIdx.x * 64, sc = blockIdx.y;
    const int c = lane & 15, g = lane >> 4;
    const int trow = t0 + wv * 16 + c;

    bf16x8 qf[4];
    const bf16* qrow = QK + (size_t)(b * NT + trow) * 256;
#pragma unroll
    for (int ks = 0; ks < 4; ++ks) qf[ks] = *(const bf16x8*)(qrow + ks * 32 + g * 8);

    const float mrow = mfin[b * NT + trow];
    const float lrow = linv[b * NT + trow];
    float* orow = out_att + (size_t)(b * NT + trow) * NT;

    for (int tt = 0; tt < SCH / 64; ++tt) {
        const int s0 = sc * SCH + tt * 64;
        __syncthreads();
        for (int cch = tid; cch < 1024; cch += 256) {
            const int row = cch >> 4, cc = cch & 15;
            *(bf16x8*)((char*)Kt + row * 256 + ((cc * 16) ^ ((row & 7) << 4))) =
                *(const bf16x8*)(QK + (size_t)(b * NT + s0 + row) * 256 + NA + cc * 8);
        }
        __syncthreads();
#pragma unroll
        for (int ns = 0; ns < 4; ++ns) {
            f32x4 acc = f32x4{0.f, 0.f, 0.f, 0.f};
            const int rr = ns * 16 + c;
            const int rsw = (rr & 7) << 4;
#pragma unroll
            for (int ks = 0; ks < 4; ++ks) {
                const bf16x8 afr = *(const bf16x8*)((const char*)Kt + rr * 256 +
                                                    ((ks * 64 + g * 16) ^ rsw));
                acc = __builtin_amdgcn_mfma_f32_16x16x32_bf16(afr, qf[ks], acc, 0, 0, 0);
            }
            f32x4 w;
#pragma unroll
            for (int jj = 0; jj < 4; ++jj)
                w[jj] = __expf(acc[jj] * SCALE - mrow) * lrow;
            *(f32x4*)(orow + s0 + ns * 16 + g * 4) = w;
        }
    }
}

// ---------------------------------------------------------------------------
extern "C" void kernel_launch(void* const* d_in, const int* in_sizes, int n_in,
                              void* d_out, int out_size, void* d_ws, size_t ws_size,
                              hipStream_t stream) {
    const float* x  = (const float*)d_in[0];
    const float* Wq = (const float*)d_in[1];
    const float* bq = (const float*)d_in[2];
    const float* Wk = (const float*)d_in[3];
    const float* bk = (const float*)d_in[4];
    const float* Wv = (const float*)d_in[5];
    const float* bv = (const float*)d_in[6];

    float* out_w   = (float*)d_out;            // [B,T,1] = 32768
    float* out_att = (float*)d_out + NB * NT;  // [B,T,T]

    char* ws = (char*)d_ws;
    bf16*  WT   = (bf16*)ws;                         // 262144 B
    float* V    = (float*)(ws + 262144);             // 131072 B
    bf16*  QK   = (bf16*)(ws + 393216);              // 16 MB
    float* pm   = (float*)(ws + 17170432);           // 512 KB
    float* pl   = (float*)(ws + 17694720);           // 512 KB
    float* pw   = (float*)(ws + 18219008);           // 512 KB
    float* mfin = (float*)(ws + 18743296);           // 128 KB
    float* linv = (float*)(ws + 18874368);           // 128 KB

    prep_wt<<<dim3(256), dim3(256), 0, stream>>>(Wq, Wk, WT);
    norm_proj<<<dim3((NB * NT) / 16), dim3(256), 0, stream>>>(x, Wv, bv, WT, bq, bk, QK, V);
    attn_pass1<<<dim3(NT / 64, NCH, NB), dim3(256), 0, stream>>>(QK, V, pm, pl, pw);
    attn_reduce<<<dim3((NB * NT) / 256), dim3(256), 0, stream>>>(pm, pl, pw, mfin, linv, out_w);
    attn_pass2<<<dim3(NT / 64, NCH, NB), dim3(256), 0, stream>>>(QK, mfin, linv, out_att);
}

// Round 4
// 175.774 us; speedup vs baseline: 1.4556x; 1.1260x over previous
//
#include <hip/hip_runtime.h>

// Problem constants (B=16, T=2048, D=512, A=128)
#define NB 16
#define NT 2048
#define ND 512
#define NA 128
#define EPSV 1e-6f
#define SCALE 0.08838834764831845f  // 128^-0.5
#define NCH 4        // s-chunks in attention
#define SCH 512      // s-chunk length

typedef __bf16 bf16;
typedef __bf16 bf16x4 __attribute__((ext_vector_type(4)));
typedef __bf16 bf16x8 __attribute__((ext_vector_type(8)));
typedef float f32x4 __attribute__((ext_vector_type(4)));

// ---------------------------------------------------------------------------
// Kernel 0: build W^T bf16 [256][512]  (rows 0..127 = Wq cols, 128..255 = Wk)
// ---------------------------------------------------------------------------
__global__ void prep_wt(const float* __restrict__ Wq, const float* __restrict__ Wk,
                        bf16* __restrict__ WT) {
    int n = blockIdx.x;
    const float* W = (n < NA) ? Wq : Wk;
    int col = n & (NA - 1);
    for (int k = threadIdx.x; k < ND; k += blockDim.x)
        WT[(size_t)n * ND + k] = (bf16)W[(size_t)k * NA + col];
}

// ---------------------------------------------------------------------------
// Kernel 1: fused norm + V + QK projection GEMM. 16 rows/block, grid 2048.
// ---------------------------------------------------------------------------
__launch_bounds__(256)
__global__ void norm_proj(const float* __restrict__ x, const float* __restrict__ Wv,
                          const float* __restrict__ bvp, const bf16* __restrict__ WT,
                          const float* __restrict__ bq, const float* __restrict__ bk,
                          bf16* __restrict__ QK, float* __restrict__ Vout) {
    __shared__ bf16 xn[16 * ND];  // 16 KB, XOR-swizzled rows
    const int tid = threadIdx.x;
    const int lane = tid & 63, wv = tid >> 6;
    const int row0 = blockIdx.x * 16;

    float wvv[8];
    float sumw = 0.f;
#pragma unroll
    for (int i = 0; i < 4; ++i) { wvv[i]     = Wv[lane * 4 + i];       sumw += wvv[i]; }
#pragma unroll
    for (int i = 0; i < 4; ++i) { wvv[4 + i] = Wv[256 + lane * 4 + i]; sumw += wvv[4 + i]; }
#pragma unroll
    for (int m = 1; m < 64; m <<= 1) sumw += __shfl_xor(sumw, m);
    const float bvs = bvp[0];

#pragma unroll
    for (int r = 0; r < 4; ++r) {
        const int lrow = wv * 4 + r;
        const int grow = row0 + lrow;
        const float* xr = x + (size_t)grow * ND;
        f32x4 a = *(const f32x4*)(xr + lane * 4);
        f32x4 b = *(const f32x4*)(xr + 256 + lane * 4);
        float s = 0.f, sq = 0.f, dw = 0.f;
#pragma unroll
        for (int i = 0; i < 4; ++i) { s += a[i]; sq += a[i] * a[i]; dw += a[i] * wvv[i]; }
#pragma unroll
        for (int i = 0; i < 4; ++i) { s += b[i]; sq += b[i] * b[i]; dw += b[i] * wvv[4 + i]; }
#pragma unroll
        for (int m = 1; m < 64; m <<= 1) {
            s  += __shfl_xor(s, m);
            sq += __shfl_xor(sq, m);
            dw += __shfl_xor(dw, m);
        }
        const float mu  = s * (1.f / 512.f);
        float var = (sq - 512.f * mu * mu) * (1.f / 511.f);
        var = fmaxf(var, 0.f);
        const float inv = 1.f / (sqrtf(var) + EPSV);
        if (lane == 0) Vout[grow] = (dw - mu * sumw) * inv + bvs;

        const int sw = (lrow & 7) << 4;
        bf16x4 v0, v1;
#pragma unroll
        for (int i = 0; i < 4; ++i) v0[i] = (bf16)((a[i] - mu) * inv);
#pragma unroll
        for (int i = 0; i < 4; ++i) v1[i] = (bf16)((b[i] - mu) * inv);
        *(bf16x4*)((char*)xn + lrow * 1024 + ((lane * 8) ^ sw))       = v0;
        *(bf16x4*)((char*)xn + lrow * 1024 + ((512 + lane * 8) ^ sw)) = v1;
    }
    __syncthreads();

    const int c = lane & 15, g = lane >> 4;
    const int asw = (c & 7) << 4;
    f32x4 acc[4];
#pragma unroll
    for (int i = 0; i < 4; ++i) acc[i] = f32x4{0.f, 0.f, 0.f, 0.f};

    for (int ks = 0; ks < 16; ++ks) {
        const bf16x8 af = *(const bf16x8*)((const char*)xn + c * 1024 +
                                           ((ks * 64 + g * 16) ^ asw));
#pragma unroll
        for (int i = 0; i < 4; ++i) {
            const int n = wv * 64 + i * 16 + c;
            const bf16x8 bfr = *(const bf16x8*)(WT + (size_t)n * ND + ks * 32 + g * 8);
            acc[i] = __builtin_amdgcn_mfma_f32_16x16x32_bf16(af, bfr, acc[i], 0, 0, 0);
        }
    }
#pragma unroll
    for (int i = 0; i < 4; ++i) {
        const int n = wv * 64 + i * 16 + c;
        const float bias = (n < NA) ? bq[n] : bk[n - NA];
#pragma unroll
        for (int j = 0; j < 4; ++j)
            QK[(size_t)(row0 + g * 4 + j) * 256 + n] = (bf16)(acc[i][j] + bias);
    }
}

// ---------------------------------------------------------------------------
// Kernel 2: pass1 — per-chunk sums l = sum(exp s), w = sum(exp s * V).
// No max (scores bounded, f32-safe). Reg-staged async K pipeline.
// ---------------------------------------------------------------------------
__launch_bounds__(256)
__global__ void attn_pass1(const bf16* __restrict__ QK, const float* __restrict__ Vg,
                           float* __restrict__ pl, float* __restrict__ pw) {
    __shared__ bf16 Kt[64 * NA];  // 16 KB, XOR-swizzled
    const int tid = threadIdx.x;
    const int lane = tid & 63, wv = tid >> 6;
    const int b = blockIdx.z, t0 = blockIdx.x * 64, sc = blockIdx.y;
    const int c = lane & 15, g = lane >> 4;
    const int trow = t0 + wv * 16 + c;

    bf16x8 qf[4];
    const bf16* qrow = QK + (size_t)(b * NT + trow) * 256;
#pragma unroll
    for (int ks = 0; ks < 4; ++ks) qf[ks] = *(const bf16x8*)(qrow + ks * 32 + g * 8);

    // staging map: thread covers rows srow + i*16 (i=0..3), 16B at col scc
    const int srow = tid >> 4, scc = tid & 15;
    const bf16* kbase = QK + (size_t)(b * NT + sc * SCH + srow) * 256 + NA + scc * 8;
    bf16* kdst = (bf16*)((char*)Kt + srow * 256 + ((scc * 16) ^ ((srow & 7) << 4)));
    // rows srow+i*16 share (row&7) -> same XOR for all 4
    bf16x8 sreg[4];

#pragma unroll
    for (int i = 0; i < 4; ++i)
        sreg[i] = *(const bf16x8*)(kbase + (size_t)(i * 16) * 256);

    const float* vbase = Vg + b * NT + sc * SCH;
    float l_loc = 0.f, w_loc = 0.f;

    for (int tt = 0; tt < SCH / 64; ++tt) {
        __syncthreads();  // all waves done reading Kt (no-op first iter)
#pragma unroll
        for (int i = 0; i < 4; ++i)
            *(bf16x8*)((char*)kdst + i * 16 * 256) = sreg[i];
        if (tt + 1 < SCH / 64) {
            const bf16* nb = kbase + (size_t)(tt + 1) * 64 * 256;
#pragma unroll
            for (int i = 0; i < 4; ++i)
                sreg[i] = *(const bf16x8*)(nb + (size_t)(i * 16) * 256);
        }
        __syncthreads();  // Kt visible

#pragma unroll
        for (int ns = 0; ns < 4; ++ns) {
            f32x4 acc = f32x4{0.f, 0.f, 0.f, 0.f};
            const int rr = ns * 16 + c;
            const int rsw = (rr & 7) << 4;
#pragma unroll
            for (int ks = 0; ks < 4; ++ks) {
                const bf16x8 afr = *(const bf16x8*)((const char*)Kt + rr * 256 +
                                                    ((ks * 64 + g * 16) ^ rsw));
                acc = __builtin_amdgcn_mfma_f32_16x16x32_bf16(afr, qf[ks], acc, 0, 0, 0);
            }
            const f32x4 vv = *(const f32x4*)(vbase + tt * 64 + ns * 16 + g * 4);
#pragma unroll
            for (int jj = 0; jj < 4; ++jj) {
                const float p = __expf(acc[jj] * SCALE);
                l_loc += p;
                w_loc += p * vv[jj];
            }
        }
    }

    // merge partials across the 4 g-lanes sharing trow
#pragma unroll
    for (int mask = 16; mask <= 32; mask <<= 1) {
        l_loc += __shfl_xor(l_loc, mask);
        w_loc += __shfl_xor(w_loc, mask);
    }
    if (g == 0) {
        const int idx = sc * (NB * NT) + b * NT + trow;
        pl[idx] = l_loc;
        pw[idx] = w_loc;
    }
}

// ---------------------------------------------------------------------------
// Kernel 3: merge the 4 chunk-partials -> 1/l, out_w
// ---------------------------------------------------------------------------
__global__ void attn_reduce(const float* __restrict__ pl, const float* __restrict__ pw,
                            float* __restrict__ linv, float* __restrict__ out_w) {
    const int r = blockIdx.x * 256 + threadIdx.x;  // 0 .. NB*NT-1
    float L = 0.f, W = 0.f;
#pragma unroll
    for (int ch = 0; ch < NCH; ++ch) {
        L += pl[ch * (NB * NT) + r];
        W += pw[ch * (NB * NT) + r];
    }
    linv[r] = 1.f / L;
    out_w[r] = W / L;
}

// ---------------------------------------------------------------------------
// Kernel 4: pass2 — recompute scores, write normalized w_att.
// Same async reg-staged pipeline; f32x4 coalesced stores.
// ---------------------------------------------------------------------------
__launch_bounds__(256)
__global__ void attn_pass2(const bf16* __restrict__ QK, const float* __restrict__ linv,
                           float* __restrict__ out_att) {
    __shared__ bf16 Kt[64 * NA];
    const int tid = threadIdx.x;
    const int lane = tid & 63, wv = tid >> 6;
    const int b = blockIdx.z, t0 = blockIdx.x * 64, sc = blockIdx.y;
    const int c = lane & 15, g = lane >> 4;
    const int trow = t0 + wv * 16 + c;

    bf16x8 qf[4];
    const bf16* qrow = QK + (size_t)(b * NT + trow) * 256;
#pragma unroll
    for (int ks = 0; ks < 4; ++ks) qf[ks] = *(const bf16x8*)(qrow + ks * 32 + g * 8);

    const int srow = tid >> 4, scc = tid & 15;
    const bf16* kbase = QK + (size_t)(b * NT + sc * SCH + srow) * 256 + NA + scc * 8;
    bf16* kdst = (bf16*)((char*)Kt + srow * 256 + ((scc * 16) ^ ((srow & 7) << 4)));
    bf16x8 sreg[4];

#pragma unroll
    for (int i = 0; i < 4; ++i)
        sreg[i] = *(const bf16x8*)(kbase + (size_t)(i * 16) * 256);

    const float lrow = linv[b * NT + trow];
    float* orow = out_att + (size_t)(b * NT + trow) * NT;

    for (int tt = 0; tt < SCH / 64; ++tt) {
        __syncthreads();
#pragma unroll
        for (int i = 0; i < 4; ++i)
            *(bf16x8*)((char*)kdst + i * 16 * 256) = sreg[i];
        if (tt + 1 < SCH / 64) {
            const bf16* nb = kbase + (size_t)(tt + 1) * 64 * 256;
#pragma unroll
            for (int i = 0; i < 4; ++i)
                sreg[i] = *(const bf16x8*)(nb + (size_t)(i * 16) * 256);
        }
        __syncthreads();

        const int s0 = sc * SCH + tt * 64;
#pragma unroll
        for (int ns = 0; ns < 4; ++ns) {
            f32x4 acc = f32x4{0.f, 0.f, 0.f, 0.f};
            const int rr = ns * 16 + c;
            const int rsw = (rr & 7) << 4;
#pragma unroll
            for (int ks = 0; ks < 4; ++ks) {
                const bf16x8 afr = *(const bf16x8*)((const char*)Kt + rr * 256 +
                                                    ((ks * 64 + g * 16) ^ rsw));
                acc = __builtin_amdgcn_mfma_f32_16x16x32_bf16(afr, qf[ks], acc, 0, 0, 0);
            }
            f32x4 w;
#pragma unroll
            for (int jj = 0; jj < 4; ++jj)
                w[jj] = __expf(acc[jj] * SCALE) * lrow;
            *(f32x4*)(orow + s0 + ns * 16 + g * 4) = w;
        }
    }
}

// ---------------------------------------------------------------------------
extern "C" void kernel_launch(void* const* d_in, const int* in_sizes, int n_in,
                              void* d_out, int out_size, void* d_ws, size_t ws_size,
                              hipStream_t stream) {
    const float* x  = (const float*)d_in[0];
    const float* Wq = (const float*)d_in[1];
    const float* bq = (const float*)d_in[2];
    const float* Wk = (const float*)d_in[3];
    const float* bk = (const float*)d_in[4];
    const float* Wv = (const float*)d_in[5];
    const float* bv = (const float*)d_in[6];

    float* out_w   = (float*)d_out;            // [B,T,1] = 32768
    float* out_att = (float*)d_out + NB * NT;  // [B,T,T]

    char* ws = (char*)d_ws;
    bf16*  WT   = (bf16*)ws;                         // 262144 B
    float* V    = (float*)(ws + 262144);             // 131072 B
    bf16*  QK   = (bf16*)(ws + 393216);              // 16 MB
    float* pl   = (float*)(ws + 17170432);           // 512 KB
    float* pw   = (float*)(ws + 17694720);           // 512 KB
    float* linv = (float*)(ws + 18219008);           // 128 KB

    prep_wt<<<dim3(256), dim3(256), 0, stream>>>(Wq, Wk, WT);
    norm_proj<<<dim3((NB * NT) / 16), dim3(256), 0, stream>>>(x, Wv, bv, WT, bq, bk, QK, V);
    attn_pass1<<<dim3(NT / 64, NCH, NB), dim3(256), 0, stream>>>(QK, V, pl, pw);
    attn_reduce<<<dim3((NB * NT) / 256), dim3(256), 0, stream>>>(pl, pw, linv, out_w);
    attn_pass2<<<dim3(NT / 64, NCH, NB), dim3(256), 0, stream>>>(QK, linv, out_att);
}